// Round 2
// baseline (457.264 us; speedup 1.0000x reference)
//
#include <hip/hip_runtime.h>

#define S_LEN 4096
#define E_DIM 1024
#define NH 8
#define DKD 128

typedef __attribute__((ext_vector_type(8))) short short8;
typedef __attribute__((ext_vector_type(4))) float f32x4;
typedef __attribute__((ext_vector_type(16))) float f32x16;
typedef __attribute__((ext_vector_type(4))) unsigned short ushort4v;

#if __has_builtin(__builtin_amdgcn_exp2f)
#define EXP2F(x) __builtin_amdgcn_exp2f(x)
#else
#define EXP2F(x) exp2f(x)
#endif

// log2(e)/sqrt(128): folded into Q so QK^T scores are already in exp2 domain
#define QSCALE 0.12753819953924682f

__device__ __forceinline__ unsigned short f32_to_bf16(float f) {
  union { float f; unsigned u; } v; v.f = f;
  unsigned r = v.u + 0x7FFFu + ((v.u >> 16) & 1u);   // RNE
  return (unsigned short)(r >> 16);
}
__device__ __forceinline__ float bf16_to_f32(unsigned short h) {
  union { unsigned u; float f; } v; v.u = ((unsigned)h) << 16; return v.f;
}

__device__ __forceinline__ void gld_lds16(const unsigned short* g, unsigned short* l) {
  __builtin_amdgcn_global_load_lds(
      (const __attribute__((address_space(1))) void*)g,
      (__attribute__((address_space(3))) void*)l, 16, 0, 0);
}

// pack 2 f32 -> 1 dword of 2 bf16 (RNE); no builtin on gfx950 (m240)
__device__ __forceinline__ unsigned cvtpk_bf16(float lo, float hi) {
  unsigned r;
  asm("v_cvt_pk_bf16_f32 %0, %1, %2" : "=v"(r) : "v"(lo), "v"(hi));
  return r;
}
// exchange: a.hi-lanes <-> b.lo-lanes (T12 idiom). After the swap both regs are
// fully-usable output words for all 64 lanes.
__device__ __forceinline__ void pl32swap(unsigned &a, unsigned &b) {
  asm volatile("v_permlane32_swap_b32 %0, %1" : "+v"(a), "+v"(b));
}

// ---------------- fused fp32 -> bf16 conversion, all 7 tensors, 1 launch ----------------
// y: 0,1,2 = q,k,v (4M elems) -> XB; 3,4,5 = Wq,Wk,Wv -> ws+2MB..; 6 = Wo -> ws+0
__global__ __launch_bounds__(256) void cvt_all(const float* __restrict__ q,
                                               const float* __restrict__ k,
                                               const float* __restrict__ v,
                                               const float* __restrict__ wq,
                                               const float* __restrict__ wk,
                                               const float* __restrict__ wv,
                                               const float* __restrict__ wo,
                                               unsigned short* __restrict__ wsbase) {
  const int y = blockIdx.y;
  const int n = (y < 3) ? (S_LEN * E_DIM) : (E_DIM * E_DIM);
  int i = (blockIdx.x * 256 + threadIdx.x) * 4;
  if (i >= n) return;
  const float* src;
  unsigned short* d;
  const size_t MBe = 512 * 1024;  // elems per MB
  switch (y) {
    case 0: src = q;  d = wsbase + 8 * MBe; break;
    case 1: src = k;  d = wsbase + 16 * MBe; break;
    case 2: src = v;  d = wsbase + 24 * MBe; break;
    case 3: src = wq; d = wsbase + 2 * MBe; break;
    case 4: src = wk; d = wsbase + 4 * MBe; break;
    case 5: src = wv; d = wsbase + 6 * MBe; break;
    default: src = wo; d = wsbase; break;
  }
  f32x4 val = *(const f32x4*)(src + i);
  uint2 pk;
  pk.x = (unsigned)f32_to_bf16(val.x) | ((unsigned)f32_to_bf16(val.y) << 16);
  pk.y = (unsigned)f32_to_bf16(val.z) | ((unsigned)f32_to_bf16(val.w) << 16);
  *(uint2*)(d + i) = pk;
}

// ---------------- G2 build: mask/gp -> bf16, permuted to MFMA C-register order ----
// G2[t>>5][s][32] where inner idx = hi*16 + reg and 32x32 C-layout maps
// reg r (0..15), hi (0..1) -> t_local = (r&3) + 8*(r>>2) + 4*hi.
// In attn each lane (q = lane&31, hi) then loads its 16 G values as two
// contiguous short8s. masked (mask==0) entries encode as bf16(-1) = 0xBF80.
__global__ __launch_bounds__(256) void build_gt(const int* __restrict__ mask,
                                                const float* __restrict__ gp,
                                                unsigned short* __restrict__ G2) {
  __shared__ unsigned short T[64][68];   // [s_local][t_local]
  const int s0 = blockIdx.x * 64, t0 = blockIdx.y * 64;
  const int tid = threadIdx.x;
  const int r = tid >> 2;              // s_local
  const int c0 = (tid & 3) * 16;       // t_local
  const size_t base = (size_t)(s0 + r) * S_LEN + t0 + c0;
#pragma unroll
  for (int j = 0; j < 16; j += 4) {
    int4 m4 = *(const int4*)(mask + base + j);
    f32x4 g4 = *(const f32x4*)(gp + base + j);
    unsigned long long w =
        (unsigned long long)(m4.x ? f32_to_bf16(g4.x) : 0xBF80u)
      | ((unsigned long long)(m4.y ? f32_to_bf16(g4.y) : 0xBF80u) << 16)
      | ((unsigned long long)(m4.z ? f32_to_bf16(g4.z) : 0xBF80u) << 32)
      | ((unsigned long long)(m4.w ? f32_to_bf16(g4.w) : 0xBF80u) << 48);
    *(unsigned long long*)&T[r][c0 + j] = w;
  }
  __syncthreads();
  // output: thread -> (s = tid>>2, tb = (tid>>1)&1, hi2 = tid&1)
  const int s = tid >> 2, tb = (tid >> 1) & 1, hi2 = tid & 1;
  __attribute__((aligned(16))) unsigned long long tmp[4];
#pragma unroll
  for (int m = 0; m < 4; ++m)   // idx = hi2*16 + m*4 + a  <->  t = m*8 + hi2*4 + a
    tmp[m] = *(const unsigned long long*)&T[s][tb * 32 + m * 8 + hi2 * 4];
  const size_t tbg = (size_t)(t0 >> 5) + tb;
  unsigned short* dst = G2 + (tbg * S_LEN + s0 + s) * 32 + hi2 * 16;
  *(f32x4*)dst = ((const f32x4*)tmp)[0];
  *(f32x4*)(dst + 8) = ((const f32x4*)tmp)[1];
}

// XOR chunk swizzle for 64B-row LDS tiles: stored slot = chunk ^ ((row>>1)&3).
#define SSW(lane) ((((lane) & 3) ^ (((lane) >> 3) & 3)) * 8)
#define KSWZ(quad, l15) ((((quad) ^ (((l15) >> 1) & 3))) * 8)

// ---------------- 128x128 bf16 GEMM core: C = A[M,K] * B[N,K]^T ----------------
__device__ __forceinline__ void gemm128_v3(const unsigned short* __restrict__ A,
                                           const unsigned short* __restrict__ B,
                                           int row0, int col0, int K,
                                           unsigned short* As, unsigned short* Bs,
                                           f32x4 acc[4][4]) {
  const int tid = threadIdx.x, lane = tid & 63, wave = tid >> 6;
  const int quad = lane >> 4, l15 = lane & 15;
  const int wm = (wave >> 1) * 64, wn = (wave & 1) * 64;
  const int sr = wave * 32 + (lane >> 2);
  const int ssw = SSW(lane);
  const int kswz = KSWZ(quad, l15);
  const unsigned short* gA = A + (size_t)(row0 + sr) * K + ssw;
  const unsigned short* gB = B + (size_t)(col0 + sr) * K + ssw;
  unsigned short* lA = As + wave * 32 * 32;
  unsigned short* lB = Bs + wave * 32 * 32;
  for (int k0 = 0; k0 < K; k0 += 32) {
    __syncthreads();
    gld_lds16(gA + k0, lA);
    gld_lds16(gA + k0 + (size_t)16 * K, lA + 16 * 32);
    gld_lds16(gB + k0, lB);
    gld_lds16(gB + k0 + (size_t)16 * K, lB + 16 * 32);
    __syncthreads();
    short8 a[4], b[4];
#pragma unroll
    for (int mt = 0; mt < 4; ++mt)
      a[mt] = *(const short8*)(As + (wm + mt * 16 + l15) * 32 + kswz);
#pragma unroll
    for (int nt = 0; nt < 4; ++nt)
      b[nt] = *(const short8*)(Bs + (wn + nt * 16 + l15) * 32 + kswz);
#pragma unroll
    for (int mt = 0; mt < 4; ++mt)
#pragma unroll
      for (int nt = 0; nt < 4; ++nt)
        acc[mt][nt] = __builtin_amdgcn_mfma_f32_16x16x32_bf16(a[mt], b[nt], acc[mt][nt], 0, 0, 0);
  }
}

// ---------------- QKV projection ----------------
__global__ __launch_bounds__(256) void proj_qkv(
    const unsigned short* __restrict__ xb, const unsigned short* __restrict__ Wb,
    const float* __restrict__ bq, const float* __restrict__ bk, const float* __restrict__ bv,
    unsigned short* __restrict__ Qh, unsigned short* __restrict__ Kh,
    unsigned short* __restrict__ Vt) {
  __shared__ __attribute__((aligned(16))) unsigned short As[128 * 32];
  __shared__ __attribute__((aligned(16))) unsigned short Bs[128 * 32];
  const int z = blockIdx.z;
  const unsigned short* X = xb + (size_t)z * S_LEN * E_DIM;
  const unsigned short* W = Wb + (size_t)z * E_DIM * E_DIM;
  const float* bias = (z == 0) ? bq : (z == 1) ? bk : bv;
  const f32x4 zero4 = {0.f, 0.f, 0.f, 0.f};
  f32x4 acc[4][4];
#pragma unroll
  for (int i = 0; i < 4; ++i)
#pragma unroll
    for (int j = 0; j < 4; ++j) acc[i][j] = zero4;
  const int lane = threadIdx.x & 63, wave = threadIdx.x >> 6;
  const int quad = lane >> 4, l15 = lane & 15;
  const int wm = (wave >> 1) * 64, wn = (wave & 1) * 64;
  if (z < 2) {
    const int row0 = blockIdx.y * 128;   // e
    const int col0 = blockIdx.x * 128;   // s
    gemm128_v3(W, X, row0, col0, E_DIM, As, Bs, acc);
    unsigned short* Out = (z == 0) ? Qh : Kh;
    const float scale = (z == 0) ? QSCALE : 1.0f;
#pragma unroll
    for (int mt = 0; mt < 4; ++mt) {
      int ge = row0 + wm + mt * 16 + quad * 4;
      f32x4 b4 = *(const f32x4*)(bias + ge);
#pragma unroll
      for (int nt = 0; nt < 4; ++nt) {
        int gs = col0 + wn + nt * 16 + l15;
        ushort4v pk;
#pragma unroll
        for (int r = 0; r < 4; ++r) pk[r] = f32_to_bf16((acc[mt][nt][r] + b4[r]) * scale);
        *(ushort4v*)(Out + (size_t)gs * E_DIM + ge) = pk;
      }
    }
  } else {
    const int row0 = blockIdx.x * 128;   // s
    const int col0 = blockIdx.y * 128;   // e
    gemm128_v3(X, W, row0, col0, E_DIM, As, Bs, acc);
#pragma unroll
    for (int nt = 0; nt < 4; ++nt) {
      int ge = col0 + wn + nt * 16 + l15;
      float bv_ = bias[ge];
#pragma unroll
      for (int mt = 0; mt < 4; ++mt) {
        int gs = row0 + wm + mt * 16 + quad * 4;
        ushort4v pk;
#pragma unroll
        for (int r = 0; r < 4; ++r) pk[r] = f32_to_bf16(acc[mt][nt][r] + bv_);
        *(ushort4v*)(Vt + (size_t)ge * S_LEN + gs) = pk;   // V^T [e][s]
      }
    }
  }
}

// ---------------- output projection + bias + residual: 64e x 128s tiles ----------------
__global__ __launch_bounds__(256) void out_proj(
    const unsigned short* __restrict__ Zb, const unsigned short* __restrict__ Wob,
    const float* __restrict__ bo, const float* __restrict__ resid,
    float* __restrict__ Y) {
  __shared__ __attribute__((aligned(16))) unsigned short As[64 * 32];
  __shared__ __attribute__((aligned(16))) unsigned short Bs[128 * 32];
  const int row0 = blockIdx.y * 64;   // e
  const int col0 = blockIdx.x * 128;  // s
  const int tid = threadIdx.x, lane = tid & 63, wave = tid >> 6;
  const int quad = lane >> 4, l15 = lane & 15;
  const int wm = (wave >> 1) * 32, wn = (wave & 1) * 64;
  const int ssw = SSW(lane);
  const int kswz = KSWZ(quad, l15);
  const f32x4 zero4 = {0.f, 0.f, 0.f, 0.f};
  f32x4 acc[2][4];
#pragma unroll
  for (int i = 0; i < 2; ++i)
#pragma unroll
    for (int j = 0; j < 4; ++j) acc[i][j] = zero4;
  const unsigned short* gA = Wob + (size_t)(row0 + wave * 16 + (lane >> 2)) * E_DIM + ssw;
  const unsigned short* gB = Zb + (size_t)(col0 + wave * 32 + (lane >> 2)) * E_DIM + ssw;
  unsigned short* lA = As + wave * 16 * 32;
  unsigned short* lB = Bs + wave * 32 * 32;
  for (int k0 = 0; k0 < E_DIM; k0 += 32) {
    __syncthreads();
    gld_lds16(gA + k0, lA);
    gld_lds16(gB + k0, lB);
    gld_lds16(gB + k0 + (size_t)16 * E_DIM, lB + 16 * 32);
    __syncthreads();
    short8 a[2], b[4];
#pragma unroll
    for (int mt = 0; mt < 2; ++mt)
      a[mt] = *(const short8*)(As + (wm + mt * 16 + l15) * 32 + kswz);
#pragma unroll
    for (int nt = 0; nt < 4; ++nt)
      b[nt] = *(const short8*)(Bs + (wn + nt * 16 + l15) * 32 + kswz);
#pragma unroll
    for (int mt = 0; mt < 2; ++mt)
#pragma unroll
      for (int nt = 0; nt < 4; ++nt)
        acc[mt][nt] = __builtin_amdgcn_mfma_f32_16x16x32_bf16(a[mt], b[nt], acc[mt][nt], 0, 0, 0);
  }
#pragma unroll
  for (int mt = 0; mt < 2; ++mt) {
    int ge = row0 + wm + mt * 16 + quad * 4;
    f32x4 b4 = *(const f32x4*)(bo + ge);
#pragma unroll
    for (int nt = 0; nt < 4; ++nt) {
      int gs = col0 + wn + nt * 16 + l15;
      f32x4 r4 = *(const f32x4*)(resid + (size_t)gs * E_DIM + ge);
      f32x4 ov = acc[mt][nt] + b4 + r4;
      *(f32x4*)(Y + (size_t)gs * E_DIM + ge) = ov;
    }
  }
}

// ---------------- flash attention: fragment-major LDS, fully linear ds ops ----------------
// grid (32 qt, 8 h, 3 ts) = 768 blocks -> 3 blocks/CU (LDS 32768 B).
// LDS layout: K'/V' are stored as 16 regions of 1KiB, one MFMA operand slice each;
// lane l's 16B lives at region*1024 + l*16. All ds_read_b128 in the loop are then
// ONE base VGPR + immediate offset, 64 lanes covering 1024 contiguous bytes ->
// provably conflict-free (and matches the gld_lds16 linear write exactly).
// The per-lane GATHER happens on the global_load_lds SOURCE address (m173 pattern).
//   K region j = ks*2 + half : lane(l31,hi) <- K[tbase+t0+half*32+l31][h*128+ks*16+hi*8]
//   V region j = db*4 + tc   : lane(l31,hi) <- V^T[h*128+db*32+l31][tbase+t0+tc*16+hi*8]
// Per iter: QK(Ks) -> barrierA -> issue K(t+1) -> softmax+P(in-reg, T12) -> PV(Vs)
// -> barrierB -> issue V(t+1). Staging drains one barrier late, under compute.
__global__ __launch_bounds__(256, 3) void attn_fwd(
    const unsigned short* __restrict__ Qh, const unsigned short* __restrict__ Kh,
    const unsigned short* __restrict__ Vt, const unsigned short* __restrict__ G2,
    unsigned short* __restrict__ OP, float* __restrict__ LP) {
  __shared__ __attribute__((aligned(16))) unsigned short Ks[16 * 512];  // 16 KiB
  __shared__ __attribute__((aligned(16))) unsigned short Vs[16 * 512];  // 16 KiB
  const int qt = blockIdx.x, h = blockIdx.y, ts = blockIdx.z;
  const int q0 = qt * 128;
  const int tbase = (ts == 0) ? 0 : (1408 + 1344 * (ts - 1));
  const int niter = (ts == 0) ? 22 : 21;
  const int tid = threadIdx.x;
  const int wv = tid >> 6, lane = tid & 63;
  const int l31 = lane & 31, hi = lane >> 5;

  // staging pointers: wave wv owns K regions j=wv*4+c and V regions j=wv*4+c (db=wv,tc=c)
  const unsigned short* gK[4];
  const unsigned short* gV[4];
#pragma unroll
  for (int c = 0; c < 4; ++c) {
    const int j = wv * 4 + c;
    gK[c] = Kh + (size_t)(tbase + (j & 1) * 32 + l31) * E_DIM + h * DKD + (j >> 1) * 16 + hi * 8;
    gV[c] = Vt + (size_t)(h * DKD + wv * 32 + l31) * S_LEN + tbase + c * 16 + hi * 8;
  }
  unsigned short* lKb = Ks + wv * 4 * 512;
  unsigned short* lVb = Vs + wv * 4 * 512;

  // Q B-fragments in registers: Q[q = q0+wv*32+l31][ks*16 + hi*8 + j] (pre-scaled)
  short8 aq[8];
  {
    const unsigned short* qp =
        Qh + (size_t)(q0 + wv * 32 + l31) * E_DIM + h * DKD + hi * 8;
#pragma unroll
    for (int ks = 0; ks < 8; ++ks) aq[ks] = *(const short8*)(qp + ks * 16);
  }

  // per-lane LDS read bases (all reads are base + compile-time immediate)
  const unsigned short* ksl = Ks + lane * 8;
  const unsigned short* vsl = Vs + lane * 8;
  const unsigned short* g2p =
      G2 + ((size_t)(tbase >> 5) * S_LEN + q0 + wv * 32 + l31) * 32 + hi * 16;

  float l_acc = 0.0f;
  f32x16 z16;
#pragma unroll
  for (int j = 0; j < 16; ++j) z16[j] = 0.0f;   // loop-invariant zero C operand
  f32x16 o[4];
#pragma unroll
  for (int d = 0; d < 4; ++d) o[d] = z16;

  // prologue: stage tile 0, then advance
#pragma unroll
  for (int c = 0; c < 4; ++c) {
    gld_lds16(gK[c], lKb + c * 512);
    gld_lds16(gV[c], lVb + c * 512);
  }
#pragma unroll
  for (int c = 0; c < 4; ++c) { gK[c] += (size_t)64 * E_DIM; gV[c] += 64; }
  __syncthreads();

  for (int it = 0; it < niter; ++it) {
    // G loads (idx = hi*16 + reg matches the 32x32 C register order)
    short8 gg[4];
    gg[0] = *(const short8*)(g2p);
    gg[1] = *(const short8*)(g2p + 8);
    gg[2] = *(const short8*)(g2p + (size_t)S_LEN * 32);
    gg[3] = *(const short8*)(g2p + (size_t)S_LEN * 32 + 8);
    g2p += (size_t)2 * S_LEN * 32;

    // S^T = K Q^T (exp2 domain): col = q = l31, row = t. ks=0 peeled onto zero C.
    f32x16 sv[2];
    __builtin_amdgcn_s_setprio(1);
    {
      short8 k0 = *(const short8*)(ksl + 0 * 512);
      short8 k1 = *(const short8*)(ksl + 1 * 512);
      sv[0] = __builtin_amdgcn_mfma_f32_32x32x16_bf16(k0, aq[0], z16, 0, 0, 0);
      sv[1] = __builtin_amdgcn_mfma_f32_32x32x16_bf16(k1, aq[0], z16, 0, 0, 0);
    }
#pragma unroll
    for (int ks = 1; ks < 8; ++ks) {
      short8 k0 = *(const short8*)(ksl + (2 * ks) * 512);
      short8 k1 = *(const short8*)(ksl + (2 * ks + 1) * 512);
      sv[0] = __builtin_amdgcn_mfma_f32_32x32x16_bf16(k0, aq[ks], sv[0], 0, 0, 0);
      sv[1] = __builtin_amdgcn_mfma_f32_32x32x16_bf16(k1, aq[ks], sv[1], 0, 0, 0);
    }
    __builtin_amdgcn_s_setprio(0);
    __syncthreads();   // A: Ks consumed; drains V(t) staging + G loads

    if (it + 1 < niter) {
#pragma unroll
      for (int c = 0; c < 4; ++c) {
        gld_lds16(gK[c], lKb + c * 512);
        gK[c] += (size_t)64 * E_DIM;
      }
    }

    // softmax (fixed-base exp2, masked -> 0) + in-register P relayout (T12)
    short8 pa[4];
#pragma unroll
    for (int b = 0; b < 2; ++b) {
      float p[16];
#pragma unroll
      for (int r = 0; r < 16; ++r) {
        float gv = bf16_to_f32((unsigned short)gg[2 * b + (r >> 3)][r & 7]);
        float x = (gv < 0.0f) ? -1e9f : sv[b][r];
        float e = EXP2F(x);
        l_acc += e;
        p[r] = e * gv;
      }
#pragma unroll
      for (int c2 = 0; c2 < 2; ++c2) {
        unsigned X0 = cvtpk_bf16(p[8 * c2 + 0], p[8 * c2 + 1]);
        unsigned X1 = cvtpk_bf16(p[8 * c2 + 2], p[8 * c2 + 3]);
        unsigned X2 = cvtpk_bf16(p[8 * c2 + 4], p[8 * c2 + 5]);
        unsigned X3 = cvtpk_bf16(p[8 * c2 + 6], p[8 * c2 + 7]);
        pl32swap(X0, X2);   // -> X0 = frag word0 (j=0,1), X2 = word2 (j=4,5)
        pl32swap(X1, X3);   // -> X1 = word1 (j=2,3),      X3 = word3 (j=6,7)
        union { unsigned w[4]; short8 s8; } u;
        u.w[0] = X0; u.w[1] = X1; u.w[2] = X2; u.w[3] = X3;
        pa[2 * b + c2] = u.s8;
      }
    }

    // O += P V  (A = pa from registers, B = V' fragments from LDS, linear reads)
    __builtin_amdgcn_s_setprio(1);
#pragma unroll
    for (int db = 0; db < 4; ++db) {
#pragma unroll
      for (int tc = 0; tc < 4; ++tc) {
        short8 bv8 = *(const short8*)(vsl + (db * 4 + tc) * 512);
        o[db] = __builtin_amdgcn_mfma_f32_32x32x16_bf16(pa[tc], bv8, o[db], 0, 0, 0);
      }
    }
    __builtin_amdgcn_s_setprio(0);
    __syncthreads();   // B: Vs consumed; drains K(t+1) staging

    if (it + 1 < niter) {
#pragma unroll
      for (int c = 0; c < 4; ++c) {
        gld_lds16(gV[c], lVb + c * 512);
        gV[c] += 64;
      }
    }
  }

  // epilogue: l reduce over hi-halves; write partials
  l_acc += __shfl_xor(l_acc, 32, 64);
  if (hi == 0)
    LP[((size_t)ts * NH + h) * S_LEN + q0 + wv * 32 + l31] = l_acc;
  unsigned short* op = OP + (size_t)ts * S_LEN * E_DIM;
#pragma unroll
  for (int db = 0; db < 4; ++db)
#pragma unroll
    for (int r = 0; r < 16; ++r) {
      int gr = q0 + wv * 32 + (r & 3) + 8 * (r >> 2) + 4 * hi;
      int gc = h * DKD + db * 32 + l31;
      op[(size_t)gr * E_DIM + gc] = f32_to_bf16(o[db][r]);
    }
}

// ---------------- combine t-split partials: Z = (O0+O1+O2)/(l0+l1+l2) ----------------
__global__ __launch_bounds__(256) void combine(const unsigned short* __restrict__ OP,
                                               const float* __restrict__ LP,
                                               unsigned short* __restrict__ Z) {
  const int s = blockIdx.x;
  const int e0 = threadIdx.x * 4;
  const int h = e0 >> 7;
  const float l = LP[(size_t)h * S_LEN + s] +
                  LP[(size_t)(NH + h) * S_LEN + s] +
                  LP[(size_t)(2 * NH + h) * S_LEN + s];
  const float inv = 1.0f / l;
  const size_t sz = (size_t)S_LEN * E_DIM;
  ushort4v a = *(const ushort4v*)(OP + (size_t)s * E_DIM + e0);
  ushort4v b = *(const ushort4v*)(OP + sz + (size_t)s * E_DIM + e0);
  ushort4v c = *(const ushort4v*)(OP + 2 * sz + (size_t)s * E_DIM + e0);
  ushort4v pk;
#pragma unroll
  for (int j = 0; j < 4; ++j)
    pk[j] = f32_to_bf16((bf16_to_f32(a[j]) + bf16_to_f32(b[j]) + bf16_to_f32(c[j])) * inv);
  *(ushort4v*)(Z + (size_t)s * E_DIM + e0) = pk;
}

// ---------------- LayerNorm ----------------
__global__ __launch_bounds__(256) void ln_fwd(const float* __restrict__ Y,
                                              const float* __restrict__ g,
                                              const float* __restrict__ b,
                                              float* __restrict__ out) {
  const int row = blockIdx.x;
  const int tid = threadIdx.x;
  const float* y = Y + (size_t)row * E_DIM;
  f32x4 v = *(const f32x4*)(y + tid * 4);
  float s = v.x + v.y + v.z + v.w;
  float s2 = v.x * v.x + v.y * v.y + v.z * v.z + v.w * v.w;
#pragma unroll
  for (int off = 32; off > 0; off >>= 1) {
    s += __shfl_down(s, off, 64);
    s2 += __shfl_down(s2, off, 64);
  }
  __shared__ float red[8];
  __shared__ float mu_s, rs_s;
  const int wave = tid >> 6, lane = tid & 63;
  if (lane == 0) { red[wave] = s; red[4 + wave] = s2; }
  __syncthreads();
  if (tid == 0) {
    float ts = red[0] + red[1] + red[2] + red[3];
    float ts2 = red[4] + red[5] + red[6] + red[7];
    float mu = ts * (1.0f / E_DIM);
    float var = ts2 * (1.0f / E_DIM) - mu * mu;
    mu_s = mu;
    rs_s = rsqrtf(var + 1e-5f);
  }
  __syncthreads();
  const float mu = mu_s, rs = rs_s;
  f32x4 gg = *(const f32x4*)(g + tid * 4);
  f32x4 bb = *(const f32x4*)(b + tid * 4);
  f32x4 ov;
  ov.x = (v.x - mu) * rs * gg.x + bb.x;
  ov.y = (v.y - mu) * rs * gg.y + bb.y;
  ov.z = (v.z - mu) * rs * gg.z + bb.z;
  ov.w = (v.w - mu) * rs * gg.w + bb.w;
  *(f32x4*)(out + (size_t)row * E_DIM + tid * 4) = ov;
}

extern "C" void kernel_launch(void* const* d_in, const int* in_sizes, int n_in,
                              void* d_out, int out_size, void* d_ws, size_t ws_size,
                              hipStream_t stream) {
  const float* q   = (const float*)d_in[0];
  const float* k   = (const float*)d_in[1];
  const float* v   = (const float*)d_in[2];
  const int*  mask = (const int*)d_in[3];
  const float* gp  = (const float*)d_in[4];
  const float* Wq  = (const float*)d_in[5];
  const float* bq  = (const float*)d_in[6];
  const float* Wk  = (const float*)d_in[7];
  const float* bk  = (const float*)d_in[8];
  const float* Wv  = (const float*)d_in[9];
  const float* bv  = (const float*)d_in[10];
  const float* Wo  = (const float*)d_in[11];
  const float* bo  = (const float*)d_in[12];
  const float* lng = (const float*)d_in[13];
  const float* lnb = (const float*)d_in[14];

  char* ws = (char*)d_ws;
  const size_t MB = 1024 * 1024;
  // layout, 88 MB peak (lifetimes disjoint where overlapped):
  unsigned short* WOB  = (unsigned short*)(ws + 0);      // Wo bf16 [0,2)
  unsigned short* WQKV = (unsigned short*)(ws + 2 * MB); // Wq,Wk,Wv [2,8) dead after proj
  float* LPb = (float*)(ws + 2 * MB);                    // [2,2.4) l-partials (after proj)
  unsigned short* XB = (unsigned short*)(ws + 8 * MB);   // q,k,v bf16 [8,32) dead after proj
  unsigned short* GT = (unsigned short*)(ws + 8 * MB);   // [8,40) G2 built after proj
  unsigned short* QH = (unsigned short*)(ws + 40 * MB);  // [40,48) dead after attn
  unsigned short* KH = (unsigned short*)(ws + 48 * MB);  // [48,56) dead after attn
  unsigned short* VT = (unsigned short*)(ws + 56 * MB);  // [56,64) dead after attn
  unsigned short* ZB = (unsigned short*)(ws + 40 * MB);  // [40,48) written by combine
  float* YF = (float*)(ws + 48 * MB);                    // [48,64) written by out_proj
  unsigned short* OP = (unsigned short*)(ws + 64 * MB);  // [64,88) O-partials (3x8MB)

  cvt_all<<<dim3(4096, 7), 256, 0, stream>>>(q, k, v, Wq, Wk, Wv, Wo,
                                             (unsigned short*)ws);
  proj_qkv<<<dim3(32, 8, 3), 256, 0, stream>>>(XB, WQKV, bq, bk, bv, QH, KH, VT);
  build_gt<<<dim3(64, 64), 256, 0, stream>>>(mask, gp, GT);   // overwrites XB
  attn_fwd<<<dim3(32, 8, 3), 256, 0, stream>>>(QH, KH, VT, GT, OP, LPb);
  combine<<<S_LEN, 256, 0, stream>>>(OP, LPb, ZB);
  out_proj<<<dim3(32, 16), 256, 0, stream>>>(ZB, WOB, bo, q, YF);
  ln_fwd<<<S_LEN, 256, 0, stream>>>(YF, lng, lnb, (float*)d_out);
}

// Round 4
// 431.745 us; speedup vs baseline: 1.0591x; 1.0591x over previous
//
#include <hip/hip_runtime.h>

#define S_LEN 4096
#define E_DIM 1024
#define NH 8
#define DKD 128

typedef __attribute__((ext_vector_type(8))) short short8;
typedef __attribute__((ext_vector_type(4))) float f32x4;
typedef __attribute__((ext_vector_type(16))) float f32x16;
typedef __attribute__((ext_vector_type(4))) unsigned short ushort4v;

#if __has_builtin(__builtin_amdgcn_exp2f)
#define EXP2F(x) __builtin_amdgcn_exp2f(x)
#else
#define EXP2F(x) exp2f(x)
#endif

// log2(e)/sqrt(128): folded into Q so QK^T scores are already in exp2 domain
#define QSCALE 0.12753819953924682f

__device__ __forceinline__ unsigned short f32_to_bf16(float f) {
  union { float f; unsigned u; } v; v.f = f;
  unsigned r = v.u + 0x7FFFu + ((v.u >> 16) & 1u);   // RNE
  return (unsigned short)(r >> 16);
}
__device__ __forceinline__ float bf16_to_f32(unsigned short h) {
  union { unsigned u; float f; } v; v.u = ((unsigned)h) << 16; return v.f;
}

__device__ __forceinline__ void gld_lds16(const unsigned short* g, unsigned short* l) {
  __builtin_amdgcn_global_load_lds(
      (const __attribute__((address_space(1))) void*)g,
      (__attribute__((address_space(3))) void*)l, 16, 0, 0);
}

// pack 2 f32 -> 1 dword of 2 bf16 (RNE); no builtin on gfx950 (m240)
__device__ __forceinline__ unsigned cvtpk_bf16(float lo, float hi) {
  unsigned r;
  asm("v_cvt_pk_bf16_f32 %0, %1, %2" : "=v"(r) : "v"(lo), "v"(hi));
  return r;
}
// exchange: a.hi-lanes <-> b.lo-lanes (T12 idiom). After the swap both regs are
// fully-usable output words for all 64 lanes.
__device__ __forceinline__ void pl32swap(unsigned &a, unsigned &b) {
  asm volatile("v_permlane32_swap_b32 %0, %1" : "+v"(a), "+v"(b));
}

// ---------------- fused fp32 -> bf16 conversion, all 7 tensors, 1 launch ----------------
// y: 0,1,2 = q,k,v (4M elems) -> XB; 3,4,5 = Wq,Wk,Wv -> ws+2MB..; 6 = Wo -> ws+0
__global__ __launch_bounds__(256) void cvt_all(const float* __restrict__ q,
                                               const float* __restrict__ k,
                                               const float* __restrict__ v,
                                               const float* __restrict__ wq,
                                               const float* __restrict__ wk,
                                               const float* __restrict__ wv,
                                               const float* __restrict__ wo,
                                               unsigned short* __restrict__ wsbase) {
  const int y = blockIdx.y;
  const int n = (y < 3) ? (S_LEN * E_DIM) : (E_DIM * E_DIM);
  int i = (blockIdx.x * 256 + threadIdx.x) * 4;
  if (i >= n) return;
  const float* src;
  unsigned short* d;
  const size_t MBe = 512 * 1024;  // elems per MB
  switch (y) {
    case 0: src = q;  d = wsbase + 8 * MBe; break;
    case 1: src = k;  d = wsbase + 16 * MBe; break;
    case 2: src = v;  d = wsbase + 24 * MBe; break;
    case 3: src = wq; d = wsbase + 2 * MBe; break;
    case 4: src = wk; d = wsbase + 4 * MBe; break;
    case 5: src = wv; d = wsbase + 6 * MBe; break;
    default: src = wo; d = wsbase; break;
  }
  f32x4 val = *(const f32x4*)(src + i);
  uint2 pk;
  pk.x = (unsigned)f32_to_bf16(val.x) | ((unsigned)f32_to_bf16(val.y) << 16);
  pk.y = (unsigned)f32_to_bf16(val.z) | ((unsigned)f32_to_bf16(val.w) << 16);
  *(uint2*)(d + i) = pk;
}

// ---------------- G2 build: mask/gp -> bf16, permuted to MFMA C-register order ----
// G2[t>>5][s][32] where inner idx = hi*16 + reg and 32x32 C-layout maps
// reg r (0..15), hi (0..1) -> t_local = (r&3) + 8*(r>>2) + 4*hi.
// In attn each lane (q = lane&31, hi) then loads its 16 G values as two
// contiguous short8s. masked (mask==0) entries encode as bf16(-1) = 0xBF80.
__global__ __launch_bounds__(256) void build_gt(const int* __restrict__ mask,
                                                const float* __restrict__ gp,
                                                unsigned short* __restrict__ G2) {
  __shared__ unsigned short T[64][68];   // [s_local][t_local]
  const int s0 = blockIdx.x * 64, t0 = blockIdx.y * 64;
  const int tid = threadIdx.x;
  const int r = tid >> 2;              // s_local
  const int c0 = (tid & 3) * 16;       // t_local
  const size_t base = (size_t)(s0 + r) * S_LEN + t0 + c0;
#pragma unroll
  for (int j = 0; j < 16; j += 4) {
    int4 m4 = *(const int4*)(mask + base + j);
    f32x4 g4 = *(const f32x4*)(gp + base + j);
    unsigned long long w =
        (unsigned long long)(m4.x ? f32_to_bf16(g4.x) : 0xBF80u)
      | ((unsigned long long)(m4.y ? f32_to_bf16(g4.y) : 0xBF80u) << 16)
      | ((unsigned long long)(m4.z ? f32_to_bf16(g4.z) : 0xBF80u) << 32)
      | ((unsigned long long)(m4.w ? f32_to_bf16(g4.w) : 0xBF80u) << 48);
    *(unsigned long long*)&T[r][c0 + j] = w;
  }
  __syncthreads();
  // output: thread -> (s = tid>>2, tb = (tid>>1)&1, hi2 = tid&1)
  const int s = tid >> 2, tb = (tid >> 1) & 1, hi2 = tid & 1;
  __attribute__((aligned(16))) unsigned long long tmp[4];
#pragma unroll
  for (int m = 0; m < 4; ++m)   // idx = hi2*16 + m*4 + a  <->  t = m*8 + hi2*4 + a
    tmp[m] = *(const unsigned long long*)&T[s][tb * 32 + m * 8 + hi2 * 4];
  const size_t tbg = (size_t)(t0 >> 5) + tb;
  unsigned short* dst = G2 + (tbg * S_LEN + s0 + s) * 32 + hi2 * 16;
  *(f32x4*)dst = ((const f32x4*)tmp)[0];
  *(f32x4*)(dst + 8) = ((const f32x4*)tmp)[1];
}

// XOR chunk swizzle for 64B-row LDS tiles: stored slot = chunk ^ ((row>>1)&3).
#define SSW(lane) ((((lane) & 3) ^ (((lane) >> 3) & 3)) * 8)
#define KSWZ(quad, l15) ((((quad) ^ (((l15) >> 1) & 3))) * 8)

// ---------------- 128x128 bf16 GEMM core: C = A[M,K] * B[N,K]^T ----------------
__device__ __forceinline__ void gemm128_v3(const unsigned short* __restrict__ A,
                                           const unsigned short* __restrict__ B,
                                           int row0, int col0, int K,
                                           unsigned short* As, unsigned short* Bs,
                                           f32x4 acc[4][4]) {
  const int tid = threadIdx.x, lane = tid & 63, wave = tid >> 6;
  const int quad = lane >> 4, l15 = lane & 15;
  const int wm = (wave >> 1) * 64, wn = (wave & 1) * 64;
  const int sr = wave * 32 + (lane >> 2);
  const int ssw = SSW(lane);
  const int kswz = KSWZ(quad, l15);
  const unsigned short* gA = A + (size_t)(row0 + sr) * K + ssw;
  const unsigned short* gB = B + (size_t)(col0 + sr) * K + ssw;
  unsigned short* lA = As + wave * 32 * 32;
  unsigned short* lB = Bs + wave * 32 * 32;
  for (int k0 = 0; k0 < K; k0 += 32) {
    __syncthreads();
    gld_lds16(gA + k0, lA);
    gld_lds16(gA + k0 + (size_t)16 * K, lA + 16 * 32);
    gld_lds16(gB + k0, lB);
    gld_lds16(gB + k0 + (size_t)16 * K, lB + 16 * 32);
    __syncthreads();
    short8 a[4], b[4];
#pragma unroll
    for (int mt = 0; mt < 4; ++mt)
      a[mt] = *(const short8*)(As + (wm + mt * 16 + l15) * 32 + kswz);
#pragma unroll
    for (int nt = 0; nt < 4; ++nt)
      b[nt] = *(const short8*)(Bs + (wn + nt * 16 + l15) * 32 + kswz);
#pragma unroll
    for (int mt = 0; mt < 4; ++mt)
#pragma unroll
      for (int nt = 0; nt < 4; ++nt)
        acc[mt][nt] = __builtin_amdgcn_mfma_f32_16x16x32_bf16(a[mt], b[nt], acc[mt][nt], 0, 0, 0);
  }
}

// ---------------- QKV projection ----------------
// K and V are written in attention fragment-major layout:
//   K'[h][t64][j][lane][8] : j = (dk/16)*2 + (t%64)/32, region interior byte
//   offset for reader-lane l (l31=t%32, hi=(dk%16)/8) = l*16, i.e. idx =
//   hi*256 + l31*8 + dk%8.   1 region = one 32x32x16 MFMA A-slice = 1 KiB.
//   V'[h][t64][j][lane][8] : j = (d/32)*4 + (t%64)/16, interior idx =
//   ((t%16)/8)*256 + (d%32)*8 + t%8.
__global__ __launch_bounds__(256) void proj_qkv(
    const unsigned short* __restrict__ xb, const unsigned short* __restrict__ Wb,
    const float* __restrict__ bq, const float* __restrict__ bk, const float* __restrict__ bv,
    unsigned short* __restrict__ Qh, unsigned short* __restrict__ Kh,
    unsigned short* __restrict__ Vt) {
  __shared__ __attribute__((aligned(16))) unsigned short As[128 * 32];
  __shared__ __attribute__((aligned(16))) unsigned short Bs[128 * 32];
  const int z = blockIdx.z;
  const unsigned short* X = xb + (size_t)z * S_LEN * E_DIM;
  const unsigned short* W = Wb + (size_t)z * E_DIM * E_DIM;
  const float* bias = (z == 0) ? bq : (z == 1) ? bk : bv;
  const f32x4 zero4 = {0.f, 0.f, 0.f, 0.f};
  f32x4 acc[4][4];
#pragma unroll
  for (int i = 0; i < 4; ++i)
#pragma unroll
    for (int j = 0; j < 4; ++j) acc[i][j] = zero4;
  const int lane = threadIdx.x & 63, wave = threadIdx.x >> 6;
  const int quad = lane >> 4, l15 = lane & 15;
  const int wm = (wave >> 1) * 64, wn = (wave & 1) * 64;
  if (z < 2) {
    const int row0 = blockIdx.y * 128;   // e
    const int col0 = blockIdx.x * 128;   // s
    gemm128_v3(W, X, row0, col0, E_DIM, As, Bs, acc);
    if (z == 0) {
#pragma unroll
      for (int mt = 0; mt < 4; ++mt) {
        int ge = row0 + wm + mt * 16 + quad * 4;
        f32x4 b4 = *(const f32x4*)(bias + ge);
#pragma unroll
        for (int nt = 0; nt < 4; ++nt) {
          int gs = col0 + wn + nt * 16 + l15;
          ushort4v pk;
#pragma unroll
          for (int r = 0; r < 4; ++r) pk[r] = f32_to_bf16((acc[mt][nt][r] + b4[r]) * QSCALE);
          *(ushort4v*)(Qh + (size_t)gs * E_DIM + ge) = pk;
        }
      }
    } else {
      // K -> fragment-major K'
#pragma unroll
      for (int mt = 0; mt < 4; ++mt) {
        int ge = row0 + wm + mt * 16 + quad * 4;        // dk-dim base (4 consec)
        f32x4 b4 = *(const f32x4*)(bias + ge);
        const int hh = ge >> 7, dk0 = ge & 127;
#pragma unroll
        for (int nt = 0; nt < 4; ++nt) {
          int gs = col0 + wn + nt * 16 + l15;           // t-dim
          ushort4v pk;
#pragma unroll
          for (int r = 0; r < 4; ++r) pk[r] = f32_to_bf16(acc[mt][nt][r] + b4[r]);
          const size_t addr =
              (((size_t)(hh * 64 + (gs >> 6)) * 16) + ((dk0 >> 4) * 2 + ((gs >> 5) & 1))) * 512
              + ((dk0 >> 3) & 1) * 256 + (gs & 31) * 8 + (dk0 & 7);
          *(ushort4v*)(Kh + addr) = pk;
        }
      }
    }
  } else {
    const int row0 = blockIdx.x * 128;   // s
    const int col0 = blockIdx.y * 128;   // e
    gemm128_v3(X, W, row0, col0, E_DIM, As, Bs, acc);
    // V -> fragment-major V'
#pragma unroll
    for (int nt = 0; nt < 4; ++nt) {
      int ge = col0 + wn + nt * 16 + l15;               // d-dim
      float bv_ = bias[ge];
      const int hh = ge >> 7, d = ge & 127;
#pragma unroll
      for (int mt = 0; mt < 4; ++mt) {
        int gs = row0 + wm + mt * 16 + quad * 4;        // t-dim base (4 consec)
        ushort4v pk;
#pragma unroll
        for (int r = 0; r < 4; ++r) pk[r] = f32_to_bf16(acc[mt][nt][r] + bv_);
        const size_t addr =
            (((size_t)(hh * 64 + (gs >> 6)) * 16) + ((d >> 5) * 4 + ((gs >> 4) & 3))) * 512
            + ((gs >> 3) & 1) * 256 + (d & 31) * 8 + (gs & 7);
        *(ushort4v*)(Vt + addr) = pk;
      }
    }
  }
}

// ---------------- output projection + bias + residual: 64e x 128s tiles ----------------
__global__ __launch_bounds__(256) void out_proj(
    const unsigned short* __restrict__ Zb, const unsigned short* __restrict__ Wob,
    const float* __restrict__ bo, const float* __restrict__ resid,
    float* __restrict__ Y) {
  __shared__ __attribute__((aligned(16))) unsigned short As[64 * 32];
  __shared__ __attribute__((aligned(16))) unsigned short Bs[128 * 32];
  const int row0 = blockIdx.y * 64;   // e
  const int col0 = blockIdx.x * 128;  // s
  const int tid = threadIdx.x, lane = tid & 63, wave = tid >> 6;
  const int quad = lane >> 4, l15 = lane & 15;
  const int wm = (wave >> 1) * 32, wn = (wave & 1) * 64;
  const int ssw = SSW(lane);
  const int kswz = KSWZ(quad, l15);
  const f32x4 zero4 = {0.f, 0.f, 0.f, 0.f};
  f32x4 acc[2][4];
#pragma unroll
  for (int i = 0; i < 2; ++i)
#pragma unroll
    for (int j = 0; j < 4; ++j) acc[i][j] = zero4;
  const unsigned short* gA = Wob + (size_t)(row0 + wave * 16 + (lane >> 2)) * E_DIM + ssw;
  const unsigned short* gB = Zb + (size_t)(col0 + wave * 32 + (lane >> 2)) * E_DIM + ssw;
  unsigned short* lA = As + wave * 16 * 32;
  unsigned short* lB = Bs + wave * 32 * 32;
  for (int k0 = 0; k0 < E_DIM; k0 += 32) {
    __syncthreads();
    gld_lds16(gA + k0, lA);
    gld_lds16(gB + k0, lB);
    gld_lds16(gB + k0 + (size_t)16 * E_DIM, lB + 16 * 32);
    __syncthreads();
    short8 a[2], b[4];
#pragma unroll
    for (int mt = 0; mt < 2; ++mt)
      a[mt] = *(const short8*)(As + (wm + mt * 16 + l15) * 32 + kswz);
#pragma unroll
    for (int nt = 0; nt < 4; ++nt)
      b[nt] = *(const short8*)(Bs + (wn + nt * 16 + l15) * 32 + kswz);
#pragma unroll
    for (int mt = 0; mt < 2; ++mt)
#pragma unroll
      for (int nt = 0; nt < 4; ++nt)
        acc[mt][nt] = __builtin_amdgcn_mfma_f32_16x16x32_bf16(a[mt], b[nt], acc[mt][nt], 0, 0, 0);
  }
#pragma unroll
  for (int mt = 0; mt < 2; ++mt) {
    int ge = row0 + wm + mt * 16 + quad * 4;
    f32x4 b4 = *(const f32x4*)(bo + ge);
#pragma unroll
    for (int nt = 0; nt < 4; ++nt) {
      int gs = col0 + wn + nt * 16 + l15;
      f32x4 r4 = *(const f32x4*)(resid + (size_t)gs * E_DIM + ge);
      f32x4 ov = acc[mt][nt] + b4 + r4;
      *(f32x4*)(Y + (size_t)gs * E_DIM + ge) = ov;
    }
  }
}

// ---------------- flash attention: fragment-major everywhere ----------------
// grid (32 qt, 8 h, 3 ts) = 768 blocks -> 3 blocks/CU (LDS 32768 B).
// K'/V' global layout already matches LDS fragment regions, so staging is
// ONE contiguous 1024B read per gld_lds16 (source = base + lane*16B), LDS
// write linear, and every ds_read_b128 is base VGPR + immediate offset over
// 1024 contiguous bytes (0 bank conflicts, verified round 2).
// Per iter: QK(Ks) -> barrierA -> issue K(t+1) -> softmax+P(in-reg, T12) ->
// PV(Vs) -> barrierB -> issue V(t+1). Staging drains one barrier late.
__global__ __launch_bounds__(256, 3) void attn_fwd(
    const unsigned short* __restrict__ Qh, const unsigned short* __restrict__ Kh,
    const unsigned short* __restrict__ Vt, const unsigned short* __restrict__ G2,
    unsigned short* __restrict__ OP, float* __restrict__ LP) {
  __shared__ __attribute__((aligned(16))) unsigned short Ks[16 * 512];  // 16 KiB
  __shared__ __attribute__((aligned(16))) unsigned short Vs[16 * 512];  // 16 KiB
  const int qt = blockIdx.x, h = blockIdx.y, ts = blockIdx.z;
  const int q0 = qt * 128;
  const int tbase = (ts == 0) ? 0 : (1408 + 1344 * (ts - 1));
  const int niter = (ts == 0) ? 22 : 21;
  const int tid = threadIdx.x;
  const int wv = tid >> 6, lane = tid & 63;
  const int l31 = lane & 31, hi = lane >> 5;

  // staging: wave wv owns regions j = wv*4+c of both K' and V'; source is
  // contiguous 1024B per instruction; advances 16 regions (8192 elems) per iter.
  const size_t stg = ((size_t)(h * 64 + (tbase >> 6)) * 16 + wv * 4) * 512 + (size_t)lane * 8;
  const unsigned short* gK = Kh + stg;
  const unsigned short* gV = Vt + stg;
  unsigned short* lKb = Ks + wv * 4 * 512;
  unsigned short* lVb = Vs + wv * 4 * 512;

  // Q B-fragments in registers: Q[q = q0+wv*32+l31][ks*16 + hi*8 + j] (pre-scaled)
  short8 aq[8];
  {
    const unsigned short* qp =
        Qh + (size_t)(q0 + wv * 32 + l31) * E_DIM + h * DKD + hi * 8;
#pragma unroll
    for (int ks = 0; ks < 8; ++ks) aq[ks] = *(const short8*)(qp + ks * 16);
  }

  // per-lane LDS read bases (all reads are base + compile-time immediate)
  const unsigned short* ksl = Ks + lane * 8;
  const unsigned short* vsl = Vs + lane * 8;
  const unsigned short* g2p =
      G2 + ((size_t)(tbase >> 5) * S_LEN + q0 + wv * 32 + l31) * 32 + hi * 16;

  float l_acc = 0.0f;
  f32x16 z16;
#pragma unroll
  for (int j = 0; j < 16; ++j) z16[j] = 0.0f;   // loop-invariant zero C operand
  f32x16 o[4];
#pragma unroll
  for (int d = 0; d < 4; ++d) o[d] = z16;

  // prologue: stage tile 0, then advance
#pragma unroll
  for (int c = 0; c < 4; ++c) {
    gld_lds16(gK + c * 512, lKb + c * 512);
    gld_lds16(gV + c * 512, lVb + c * 512);
  }
  gK += 16 * 512;
  gV += 16 * 512;
  __syncthreads();

  for (int it = 0; it < niter; ++it) {
    // G loads (idx = hi*16 + reg matches the 32x32 C register order)
    short8 gg[4];
    gg[0] = *(const short8*)(g2p);
    gg[1] = *(const short8*)(g2p + 8);
    gg[2] = *(const short8*)(g2p + (size_t)S_LEN * 32);
    gg[3] = *(const short8*)(g2p + (size_t)S_LEN * 32 + 8);
    g2p += (size_t)2 * S_LEN * 32;

    // S^T = K Q^T (exp2 domain): col = q = l31, row = t. ks=0 peeled onto zero C.
    f32x16 sv[2];
    __builtin_amdgcn_s_setprio(1);
    {
      short8 k0 = *(const short8*)(ksl + 0 * 512);
      short8 k1 = *(const short8*)(ksl + 1 * 512);
      sv[0] = __builtin_amdgcn_mfma_f32_32x32x16_bf16(k0, aq[0], z16, 0, 0, 0);
      sv[1] = __builtin_amdgcn_mfma_f32_32x32x16_bf16(k1, aq[0], z16, 0, 0, 0);
    }
#pragma unroll
    for (int ks = 1; ks < 8; ++ks) {
      short8 k0 = *(const short8*)(ksl + (2 * ks) * 512);
      short8 k1 = *(const short8*)(ksl + (2 * ks + 1) * 512);
      sv[0] = __builtin_amdgcn_mfma_f32_32x32x16_bf16(k0, aq[ks], sv[0], 0, 0, 0);
      sv[1] = __builtin_amdgcn_mfma_f32_32x32x16_bf16(k1, aq[ks], sv[1], 0, 0, 0);
    }
    __builtin_amdgcn_s_setprio(0);
    __syncthreads();   // A: Ks consumed; drains V(t) staging + G loads

    if (it + 1 < niter) {
#pragma unroll
      for (int c = 0; c < 4; ++c)
        gld_lds16(gK + c * 512, lKb + c * 512);
      gK += 16 * 512;
    }

    // softmax (fixed-base exp2, masked -> 0) + in-register P relayout (T12)
    short8 pa[4];
#pragma unroll
    for (int b = 0; b < 2; ++b) {
      float p[16];
#pragma unroll
      for (int r = 0; r < 16; ++r) {
        float gv = bf16_to_f32((unsigned short)gg[2 * b + (r >> 3)][r & 7]);
        float x = (gv < 0.0f) ? -1e9f : sv[b][r];
        float e = EXP2F(x);
        l_acc += e;
        p[r] = e * gv;
      }
#pragma unroll
      for (int c2 = 0; c2 < 2; ++c2) {
        unsigned X0 = cvtpk_bf16(p[8 * c2 + 0], p[8 * c2 + 1]);
        unsigned X1 = cvtpk_bf16(p[8 * c2 + 2], p[8 * c2 + 3]);
        unsigned X2 = cvtpk_bf16(p[8 * c2 + 4], p[8 * c2 + 5]);
        unsigned X3 = cvtpk_bf16(p[8 * c2 + 6], p[8 * c2 + 7]);
        pl32swap(X0, X2);   // -> X0 = frag word0 (j=0,1), X2 = word2 (j=4,5)
        pl32swap(X1, X3);   // -> X1 = word1 (j=2,3),      X3 = word3 (j=6,7)
        union { unsigned w[4]; short8 s8; } u;
        u.w[0] = X0; u.w[1] = X1; u.w[2] = X2; u.w[3] = X3;
        pa[2 * b + c2] = u.s8;
      }
    }

    // O += P V  (A = pa from registers, B = V' fragments from LDS, linear reads)
    __builtin_amdgcn_s_setprio(1);
#pragma unroll
    for (int db = 0; db < 4; ++db) {
#pragma unroll
      for (int tc = 0; tc < 4; ++tc) {
        short8 bv8 = *(const short8*)(vsl + (db * 4 + tc) * 512);
        o[db] = __builtin_amdgcn_mfma_f32_32x32x16_bf16(pa[tc], bv8, o[db], 0, 0, 0);
      }
    }
    __builtin_amdgcn_s_setprio(0);
    __syncthreads();   // B: Vs consumed; drains K(t+1) staging

    if (it + 1 < niter) {
#pragma unroll
      for (int c = 0; c < 4; ++c)
        gld_lds16(gV + c * 512, lVb + c * 512);
      gV += 16 * 512;
    }
  }

  // epilogue: l reduce over hi-halves; write partials
  l_acc += __shfl_xor(l_acc, 32, 64);
  if (hi == 0)
    LP[((size_t)ts * NH + h) * S_LEN + q0 + wv * 32 + l31] = l_acc;
  unsigned short* op = OP + (size_t)ts * S_LEN * E_DIM;
#pragma unroll
  for (int db = 0; db < 4; ++db)
#pragma unroll
    for (int r = 0; r < 16; ++r) {
      int gr = q0 + wv * 32 + (r & 3) + 8 * (r >> 2) + 4 * hi;
      int gc = h * DKD + db * 32 + l31;
      op[(size_t)gr * E_DIM + gc] = f32_to_bf16(o[db][r]);
    }
}

// ---------------- combine t-split partials: Z = (O0+O1+O2)/(l0+l1+l2) ----------------
__global__ __launch_bounds__(256) void combine(const unsigned short* __restrict__ OP,
                                               const float* __restrict__ LP,
                                               unsigned short* __restrict__ Z) {
  const int s = blockIdx.x;
  const int e0 = threadIdx.x * 4;
  const int h = e0 >> 7;
  const float l = LP[(size_t)h * S_LEN + s] +
                  LP[(size_t)(NH + h) * S_LEN + s] +
                  LP[(size_t)(2 * NH + h) * S_LEN + s];
  const float inv = 1.0f / l;
  const size_t sz = (size_t)S_LEN * E_DIM;
  ushort4v a = *(const ushort4v*)(OP + (size_t)s * E_DIM + e0);
  ushort4v b = *(const ushort4v*)(OP + sz + (size_t)s * E_DIM + e0);
  ushort4v c = *(const ushort4v*)(OP + 2 * sz + (size_t)s * E_DIM + e0);
  ushort4v pk;
#pragma unroll
  for (int j = 0; j < 4; ++j)
    pk[j] = f32_to_bf16((bf16_to_f32(a[j]) + bf16_to_f32(b[j]) + bf16_to_f32(c[j])) * inv);
  *(ushort4v*)(Z + (size_t)s * E_DIM + e0) = pk;
}

// ---------------- LayerNorm ----------------
__global__ __launch_bounds__(256) void ln_fwd(const float* __restrict__ Y,
                                              const float* __restrict__ g,
                                              const float* __restrict__ b,
                                              float* __restrict__ out) {
  const int row = blockIdx.x;
  const int tid = threadIdx.x;
  const float* y = Y + (size_t)row * E_DIM;
  f32x4 v = *(const f32x4*)(y + tid * 4);
  float s = v.x + v.y + v.z + v.w;
  float s2 = v.x * v.x + v.y * v.y + v.z * v.z + v.w * v.w;
#pragma unroll
  for (int off = 32; off > 0; off >>= 1) {
    s += __shfl_down(s, off, 64);
    s2 += __shfl_down(s2, off, 64);
  }
  __shared__ float red[8];
  __shared__ float mu_s, rs_s;
  const int wave = tid >> 6, lane = tid & 63;
  if (lane == 0) { red[wave] = s; red[4 + wave] = s2; }
  __syncthreads();
  if (tid == 0) {
    float ts = red[0] + red[1] + red[2] + red[3];
    float ts2 = red[4] + red[5] + red[6] + red[7];
    float mu = ts * (1.0f / E_DIM);
    float var = ts2 * (1.0f / E_DIM) - mu * mu;
    mu_s = mu;
    rs_s = rsqrtf(var + 1e-5f);
  }
  __syncthreads();
  const float mu = mu_s, rs = rs_s;
  f32x4 gg = *(const f32x4*)(g + tid * 4);
  f32x4 bb = *(const f32x4*)(b + tid * 4);
  f32x4 ov;
  ov.x = (v.x - mu) * rs * gg.x + bb.x;
  ov.y = (v.y - mu) * rs * gg.y + bb.y;
  ov.z = (v.z - mu) * rs * gg.z + bb.z;
  ov.w = (v.w - mu) * rs * gg.w + bb.w;
  *(f32x4*)(out + (size_t)row * E_DIM + tid * 4) = ov;
}

extern "C" void kernel_launch(void* const* d_in, const int* in_sizes, int n_in,
                              void* d_out, int out_size, void* d_ws, size_t ws_size,
                              hipStream_t stream) {
  const float* q   = (const float*)d_in[0];
  const float* k   = (const float*)d_in[1];
  const float* v   = (const float*)d_in[2];
  const int*  mask = (const int*)d_in[3];
  const float* gp  = (const float*)d_in[4];
  const float* Wq  = (const float*)d_in[5];
  const float* bq  = (const float*)d_in[6];
  const float* Wk  = (const float*)d_in[7];
  const float* bk  = (const float*)d_in[8];
  const float* Wv  = (const float*)d_in[9];
  const float* bv  = (const float*)d_in[10];
  const float* Wo  = (const float*)d_in[11];
  const float* bo  = (const float*)d_in[12];
  const float* lng = (const float*)d_in[13];
  const float* lnb = (const float*)d_in[14];

  char* ws = (char*)d_ws;
  const size_t MB = 1024 * 1024;
  // layout, 88 MB peak (lifetimes disjoint where overlapped):
  unsigned short* WOB  = (unsigned short*)(ws + 0);      // Wo bf16 [0,2)
  unsigned short* WQKV = (unsigned short*)(ws + 2 * MB); // Wq,Wk,Wv [2,8) dead after proj
  float* LPb = (float*)(ws + 2 * MB);                    // [2,2.4) l-partials (after proj)
  unsigned short* XB = (unsigned short*)(ws + 8 * MB);   // q,k,v bf16 [8,32) dead after proj
  unsigned short* GT = (unsigned short*)(ws + 8 * MB);   // [8,40) G2 built after proj
  unsigned short* QH = (unsigned short*)(ws + 40 * MB);  // [40,48) dead after attn
  unsigned short* KH = (unsigned short*)(ws + 48 * MB);  // [48,56) K' frag-major
  unsigned short* VT = (unsigned short*)(ws + 56 * MB);  // [56,64) V' frag-major
  unsigned short* ZB = (unsigned short*)(ws + 40 * MB);  // [40,48) written by combine
  float* YF = (float*)(ws + 48 * MB);                    // [48,64) written by out_proj
  unsigned short* OP = (unsigned short*)(ws + 64 * MB);  // [64,88) O-partials (3x8MB)

  cvt_all<<<dim3(4096, 7), 256, 0, stream>>>(q, k, v, Wq, Wk, Wv, Wo,
                                             (unsigned short*)ws);
  proj_qkv<<<dim3(32, 8, 3), 256, 0, stream>>>(XB, WQKV, bq, bk, bv, QH, KH, VT);
  build_gt<<<dim3(64, 64), 256, 0, stream>>>(mask, gp, GT);   // overwrites XB
  attn_fwd<<<dim3(32, 8, 3), 256, 0, stream>>>(QH, KH, VT, GT, OP, LPb);
  combine<<<S_LEN, 256, 0, stream>>>(OP, LPb, ZB);
  out_proj<<<dim3(32, 16), 256, 0, stream>>>(ZB, WOB, bo, q, YF);
  ln_fwd<<<S_LEN, 256, 0, stream>>>(YF, lng, lnb, (float*)d_out);
}

// Round 5
// 394.962 us; speedup vs baseline: 1.1577x; 1.0931x over previous
//
#include <hip/hip_runtime.h>

#define S_LEN 4096
#define E_DIM 1024
#define NH 8
#define DKD 128

typedef __attribute__((ext_vector_type(8))) short short8;
typedef __attribute__((ext_vector_type(4))) float f32x4;
typedef __attribute__((ext_vector_type(16))) float f32x16;
typedef __attribute__((ext_vector_type(4))) unsigned short ushort4v;

#if __has_builtin(__builtin_amdgcn_exp2f)
#define EXP2F(x) __builtin_amdgcn_exp2f(x)
#else
#define EXP2F(x) exp2f(x)
#endif

// log2(e)/sqrt(128): folded into Q so QK^T scores are already in exp2 domain
#define QSCALE 0.12753819953924682f

__device__ __forceinline__ unsigned short f32_to_bf16(float f) {
  union { float f; unsigned u; } v; v.f = f;
  unsigned r = v.u + 0x7FFFu + ((v.u >> 16) & 1u);   // RNE
  return (unsigned short)(r >> 16);
}
__device__ __forceinline__ float bf16_to_f32(unsigned short h) {
  union { unsigned u; float f; } v; v.u = ((unsigned)h) << 16; return v.f;
}

__device__ __forceinline__ void gld_lds16(const unsigned short* g, unsigned short* l) {
  __builtin_amdgcn_global_load_lds(
      (const __attribute__((address_space(1))) void*)g,
      (__attribute__((address_space(3))) void*)l, 16, 0, 0);
}

// pack 2 f32 -> 1 dword of 2 bf16 (RNE); no builtin on gfx950 (m240)
__device__ __forceinline__ unsigned cvtpk_bf16(float lo, float hi) {
  unsigned r;
  asm("v_cvt_pk_bf16_f32 %0, %1, %2" : "=v"(r) : "v"(lo), "v"(hi));
  return r;
}
// exchange: a.hi-lanes <-> b.lo-lanes (T12 idiom). After the swap both regs are
// fully-usable output words for all 64 lanes.
__device__ __forceinline__ void pl32swap(unsigned &a, unsigned &b) {
  asm volatile("v_permlane32_swap_b32 %0, %1" : "+v"(a), "+v"(b));
}

// ---------------- fused fp32 -> bf16 conversion, all 7 tensors, 1 launch ----------------
// y: 0,1,2 = q,k,v (4M elems) -> XB; 3,4,5 = Wq,Wk,Wv -> ws+2MB..; 6 = Wo -> ws+0
__global__ __launch_bounds__(256) void cvt_all(const float* __restrict__ q,
                                               const float* __restrict__ k,
                                               const float* __restrict__ v,
                                               const float* __restrict__ wq,
                                               const float* __restrict__ wk,
                                               const float* __restrict__ wv,
                                               const float* __restrict__ wo,
                                               unsigned short* __restrict__ wsbase) {
  const int y = blockIdx.y;
  const int n = (y < 3) ? (S_LEN * E_DIM) : (E_DIM * E_DIM);
  int i = (blockIdx.x * 256 + threadIdx.x) * 4;
  if (i >= n) return;
  const float* src;
  unsigned short* d;
  const size_t MBe = 512 * 1024;  // elems per MB
  switch (y) {
    case 0: src = q;  d = wsbase + 8 * MBe; break;
    case 1: src = k;  d = wsbase + 16 * MBe; break;
    case 2: src = v;  d = wsbase + 24 * MBe; break;
    case 3: src = wq; d = wsbase + 2 * MBe; break;
    case 4: src = wk; d = wsbase + 4 * MBe; break;
    case 5: src = wv; d = wsbase + 6 * MBe; break;
    default: src = wo; d = wsbase; break;
  }
  f32x4 val = *(const f32x4*)(src + i);
  uint2 pk;
  pk.x = (unsigned)f32_to_bf16(val.x) | ((unsigned)f32_to_bf16(val.y) << 16);
  pk.y = (unsigned)f32_to_bf16(val.z) | ((unsigned)f32_to_bf16(val.w) << 16);
  *(uint2*)(d + i) = pk;
}

// ---------------- G2 build: mask/gp -> bf16, permuted to MFMA C-register order ----
// G2[t>>5][s][32] with interior idx = hi*16 + reg; 32x32 C-layout maps reg r, hi ->
// t_local = (r&3) + 8*(r>>2) + 4*hi, i.e. idx(t) = ((t>>2)&1)*16 + (t>>3)*4 + (t&3).
// 4 consecutive t -> 4 consecutive idx -> one 8B store per thread per s-row.
// LDS-free register transpose: thread owns a 4s x 4t block.
//   loads : per wave instruction, 4 dense 256B segments (16 lanes x 16B, consecutive)
//   stores: per wave instruction, 8 complete 64B sectors (8 tch-lanes fill bytes
//           {0,8,16,...,56} of one (tbg, s) 64B row) -> no partial-sector writes.
// masked (mask==0) entries encode as bf16(-1) = 0xBF80.
__global__ __launch_bounds__(256) void build_gt(const int* __restrict__ mask,
                                                const float* __restrict__ gp,
                                                unsigned short* __restrict__ G2) {
  const int s0 = blockIdx.x * 64, t0 = blockIdx.y * 64;
  const int tid = threadIdx.x;
  const int sblk = tid >> 4;                 // 0..15 -> s = s0 + sblk*4 + i
  const int tch = tid & 15;                  // 0..15 -> t = t0 + tch*4 .. +4
  const int s_base = s0 + sblk * 4;
  const int t_base = t0 + tch * 4;
  const int idx = ((tch & 1) << 4) + (((tch >> 1) & 3) << 2);  // hi2*16 + m*4
  const size_t tbg = (size_t)(t0 >> 5) + (tch >> 3);
#pragma unroll
  for (int i = 0; i < 4; ++i) {
    const size_t rbase = (size_t)(s_base + i) * S_LEN + t_base;
    int4 m4 = *(const int4*)(mask + rbase);
    f32x4 g4 = *(const f32x4*)(gp + rbase);
    ushort4v pk;
    pk[0] = m4.x ? f32_to_bf16(g4.x) : (unsigned short)0xBF80;
    pk[1] = m4.y ? f32_to_bf16(g4.y) : (unsigned short)0xBF80;
    pk[2] = m4.z ? f32_to_bf16(g4.z) : (unsigned short)0xBF80;
    pk[3] = m4.w ? f32_to_bf16(g4.w) : (unsigned short)0xBF80;
    *(ushort4v*)(G2 + (tbg * S_LEN + s_base + i) * 32 + idx) = pk;
  }
}

// XOR chunk swizzle for 64B-row LDS tiles: stored slot = chunk ^ ((row>>1)&3).
#define SSW(lane) ((((lane) & 3) ^ (((lane) >> 3) & 3)) * 8)
#define KSWZ(quad, l15) ((((quad) ^ (((l15) >> 1) & 3))) * 8)

// ---------------- 128x128 bf16 GEMM core: C = A[M,K] * B[N,K]^T ----------------
__device__ __forceinline__ void gemm128_v3(const unsigned short* __restrict__ A,
                                           const unsigned short* __restrict__ B,
                                           int row0, int col0, int K,
                                           unsigned short* As, unsigned short* Bs,
                                           f32x4 acc[4][4]) {
  const int tid = threadIdx.x, lane = tid & 63, wave = tid >> 6;
  const int quad = lane >> 4, l15 = lane & 15;
  const int wm = (wave >> 1) * 64, wn = (wave & 1) * 64;
  const int sr = wave * 32 + (lane >> 2);
  const int ssw = SSW(lane);
  const int kswz = KSWZ(quad, l15);
  const unsigned short* gA = A + (size_t)(row0 + sr) * K + ssw;
  const unsigned short* gB = B + (size_t)(col0 + sr) * K + ssw;
  unsigned short* lA = As + wave * 32 * 32;
  unsigned short* lB = Bs + wave * 32 * 32;
  for (int k0 = 0; k0 < K; k0 += 32) {
    __syncthreads();
    gld_lds16(gA + k0, lA);
    gld_lds16(gA + k0 + (size_t)16 * K, lA + 16 * 32);
    gld_lds16(gB + k0, lB);
    gld_lds16(gB + k0 + (size_t)16 * K, lB + 16 * 32);
    __syncthreads();
    short8 a[4], b[4];
#pragma unroll
    for (int mt = 0; mt < 4; ++mt)
      a[mt] = *(const short8*)(As + (wm + mt * 16 + l15) * 32 + kswz);
#pragma unroll
    for (int nt = 0; nt < 4; ++nt)
      b[nt] = *(const short8*)(Bs + (wn + nt * 16 + l15) * 32 + kswz);
#pragma unroll
    for (int mt = 0; mt < 4; ++mt)
#pragma unroll
      for (int nt = 0; nt < 4; ++nt)
        acc[mt][nt] = __builtin_amdgcn_mfma_f32_16x16x32_bf16(a[mt], b[nt], acc[mt][nt], 0, 0, 0);
  }
}

// ---------------- QKV projection ----------------
// K and V are written in attention fragment-major layout:
//   K'[h][t64][j][lane][8] : j = (dk/16)*2 + (t%64)/32, region interior byte
//   offset for reader-lane l (l31=t%32, hi=(dk%16)/8) = l*16, i.e. idx =
//   hi*256 + l31*8 + dk%8.   1 region = one 32x32x16 MFMA A-slice = 1 KiB.
//   V'[h][t64][j][lane][8] : j = (d/32)*4 + (t%64)/16, interior idx =
//   ((t%16)/8)*256 + (d%32)*8 + t%8.
__global__ __launch_bounds__(256) void proj_qkv(
    const unsigned short* __restrict__ xb, const unsigned short* __restrict__ Wb,
    const float* __restrict__ bq, const float* __restrict__ bk, const float* __restrict__ bv,
    unsigned short* __restrict__ Qh, unsigned short* __restrict__ Kh,
    unsigned short* __restrict__ Vt) {
  __shared__ __attribute__((aligned(16))) unsigned short As[128 * 32];
  __shared__ __attribute__((aligned(16))) unsigned short Bs[128 * 32];
  const int z = blockIdx.z;
  const unsigned short* X = xb + (size_t)z * S_LEN * E_DIM;
  const unsigned short* W = Wb + (size_t)z * E_DIM * E_DIM;
  const float* bias = (z == 0) ? bq : (z == 1) ? bk : bv;
  const f32x4 zero4 = {0.f, 0.f, 0.f, 0.f};
  f32x4 acc[4][4];
#pragma unroll
  for (int i = 0; i < 4; ++i)
#pragma unroll
    for (int j = 0; j < 4; ++j) acc[i][j] = zero4;
  const int lane = threadIdx.x & 63, wave = threadIdx.x >> 6;
  const int quad = lane >> 4, l15 = lane & 15;
  const int wm = (wave >> 1) * 64, wn = (wave & 1) * 64;
  if (z < 2) {
    const int row0 = blockIdx.y * 128;   // e
    const int col0 = blockIdx.x * 128;   // s
    gemm128_v3(W, X, row0, col0, E_DIM, As, Bs, acc);
    if (z == 0) {
#pragma unroll
      for (int mt = 0; mt < 4; ++mt) {
        int ge = row0 + wm + mt * 16 + quad * 4;
        f32x4 b4 = *(const f32x4*)(bias + ge);
#pragma unroll
        for (int nt = 0; nt < 4; ++nt) {
          int gs = col0 + wn + nt * 16 + l15;
          ushort4v pk;
#pragma unroll
          for (int r = 0; r < 4; ++r) pk[r] = f32_to_bf16((acc[mt][nt][r] + b4[r]) * QSCALE);
          *(ushort4v*)(Qh + (size_t)gs * E_DIM + ge) = pk;
        }
      }
    } else {
      // K -> fragment-major K'
#pragma unroll
      for (int mt = 0; mt < 4; ++mt) {
        int ge = row0 + wm + mt * 16 + quad * 4;        // dk-dim base (4 consec)
        f32x4 b4 = *(const f32x4*)(bias + ge);
        const int hh = ge >> 7, dk0 = ge & 127;
#pragma unroll
        for (int nt = 0; nt < 4; ++nt) {
          int gs = col0 + wn + nt * 16 + l15;           // t-dim
          ushort4v pk;
#pragma unroll
          for (int r = 0; r < 4; ++r) pk[r] = f32_to_bf16(acc[mt][nt][r] + b4[r]);
          const size_t addr =
              (((size_t)(hh * 64 + (gs >> 6)) * 16) + ((dk0 >> 4) * 2 + ((gs >> 5) & 1))) * 512
              + ((dk0 >> 3) & 1) * 256 + (gs & 31) * 8 + (dk0 & 7);
          *(ushort4v*)(Kh + addr) = pk;
        }
      }
    }
  } else {
    const int row0 = blockIdx.x * 128;   // s
    const int col0 = blockIdx.y * 128;   // e
    gemm128_v3(X, W, row0, col0, E_DIM, As, Bs, acc);
    // V -> fragment-major V'
#pragma unroll
    for (int nt = 0; nt < 4; ++nt) {
      int ge = col0 + wn + nt * 16 + l15;               // d-dim
      float bv_ = bias[ge];
      const int hh = ge >> 7, d = ge & 127;
#pragma unroll
      for (int mt = 0; mt < 4; ++mt) {
        int gs = row0 + wm + mt * 16 + quad * 4;        // t-dim base (4 consec)
        ushort4v pk;
#pragma unroll
        for (int r = 0; r < 4; ++r) pk[r] = f32_to_bf16(acc[mt][nt][r] + bv_);
        const size_t addr =
            (((size_t)(hh * 64 + (gs >> 6)) * 16) + ((d >> 5) * 4 + ((gs >> 4) & 3))) * 512
            + ((gs >> 3) & 1) * 256 + (d & 31) * 8 + (gs & 7);
        *(ushort4v*)(Vt + addr) = pk;
      }
    }
  }
}

// ---------------- output projection + bias + residual: 64e x 128s tiles ----------------
__global__ __launch_bounds__(256) void out_proj(
    const unsigned short* __restrict__ Zb, const unsigned short* __restrict__ Wob,
    const float* __restrict__ bo, const float* __restrict__ resid,
    float* __restrict__ Y) {
  __shared__ __attribute__((aligned(16))) unsigned short As[64 * 32];
  __shared__ __attribute__((aligned(16))) unsigned short Bs[128 * 32];
  const int row0 = blockIdx.y * 64;   // e
  const int col0 = blockIdx.x * 128;  // s
  const int tid = threadIdx.x, lane = tid & 63, wave = tid >> 6;
  const int quad = lane >> 4, l15 = lane & 15;
  const int wm = (wave >> 1) * 32, wn = (wave & 1) * 64;
  const int ssw = SSW(lane);
  const int kswz = KSWZ(quad, l15);
  const f32x4 zero4 = {0.f, 0.f, 0.f, 0.f};
  f32x4 acc[2][4];
#pragma unroll
  for (int i = 0; i < 2; ++i)
#pragma unroll
    for (int j = 0; j < 4; ++j) acc[i][j] = zero4;
  const unsigned short* gA = Wob + (size_t)(row0 + wave * 16 + (lane >> 2)) * E_DIM + ssw;
  const unsigned short* gB = Zb + (size_t)(col0 + wave * 32 + (lane >> 2)) * E_DIM + ssw;
  unsigned short* lA = As + wave * 16 * 32;
  unsigned short* lB = Bs + wave * 32 * 32;
  for (int k0 = 0; k0 < E_DIM; k0 += 32) {
    __syncthreads();
    gld_lds16(gA + k0, lA);
    gld_lds16(gB + k0, lB);
    gld_lds16(gB + k0 + (size_t)16 * E_DIM, lB + 16 * 32);
    __syncthreads();
    short8 a[2], b[4];
#pragma unroll
    for (int mt = 0; mt < 2; ++mt)
      a[mt] = *(const short8*)(As + (wm + mt * 16 + l15) * 32 + kswz);
#pragma unroll
    for (int nt = 0; nt < 4; ++nt)
      b[nt] = *(const short8*)(Bs + (wn + nt * 16 + l15) * 32 + kswz);
#pragma unroll
    for (int mt = 0; mt < 2; ++mt)
#pragma unroll
      for (int nt = 0; nt < 4; ++nt)
        acc[mt][nt] = __builtin_amdgcn_mfma_f32_16x16x32_bf16(a[mt], b[nt], acc[mt][nt], 0, 0, 0);
  }
#pragma unroll
  for (int mt = 0; mt < 2; ++mt) {
    int ge = row0 + wm + mt * 16 + quad * 4;
    f32x4 b4 = *(const f32x4*)(bo + ge);
#pragma unroll
    for (int nt = 0; nt < 4; ++nt) {
      int gs = col0 + wn + nt * 16 + l15;
      f32x4 r4 = *(const f32x4*)(resid + (size_t)gs * E_DIM + ge);
      f32x4 ov = acc[mt][nt] + b4 + r4;
      *(f32x4*)(Y + (size_t)gs * E_DIM + ge) = ov;
    }
  }
}

// ---------------- flash attention: fragment-major everywhere ----------------
// grid (32 qt, 8 h, 3 ts) = 768 blocks -> 3 blocks/CU (LDS 32768 B).
// K'/V' global layout already matches LDS fragment regions, so staging is
// ONE contiguous 1024B read per gld_lds16 (source = base + lane*16B), LDS
// write linear, and every ds_read_b128 is base VGPR + immediate offset over
// 1024 contiguous bytes (0 bank conflicts, verified round 2).
// Per iter: QK(Ks) -> barrierA -> issue K(t+1) -> softmax+P(in-reg, T12) ->
// PV(Vs) -> barrierB -> issue V(t+1). Staging drains one barrier late.
__global__ __launch_bounds__(256, 3) void attn_fwd(
    const unsigned short* __restrict__ Qh, const unsigned short* __restrict__ Kh,
    const unsigned short* __restrict__ Vt, const unsigned short* __restrict__ G2,
    unsigned short* __restrict__ OP, float* __restrict__ LP) {
  __shared__ __attribute__((aligned(16))) unsigned short Ks[16 * 512];  // 16 KiB
  __shared__ __attribute__((aligned(16))) unsigned short Vs[16 * 512];  // 16 KiB
  const int qt = blockIdx.x, h = blockIdx.y, ts = blockIdx.z;
  const int q0 = qt * 128;
  const int tbase = (ts == 0) ? 0 : (1408 + 1344 * (ts - 1));
  const int niter = (ts == 0) ? 22 : 21;
  const int tid = threadIdx.x;
  const int wv = tid >> 6, lane = tid & 63;
  const int l31 = lane & 31, hi = lane >> 5;

  // staging: wave wv owns regions j = wv*4+c of both K' and V'; source is
  // contiguous 1024B per instruction; advances 16 regions (8192 elems) per iter.
  const size_t stg = ((size_t)(h * 64 + (tbase >> 6)) * 16 + wv * 4) * 512 + (size_t)lane * 8;
  const unsigned short* gK = Kh + stg;
  const unsigned short* gV = Vt + stg;
  unsigned short* lKb = Ks + wv * 4 * 512;
  unsigned short* lVb = Vs + wv * 4 * 512;

  // Q B-fragments in registers: Q[q = q0+wv*32+l31][ks*16 + hi*8 + j] (pre-scaled)
  short8 aq[8];
  {
    const unsigned short* qp =
        Qh + (size_t)(q0 + wv * 32 + l31) * E_DIM + h * DKD + hi * 8;
#pragma unroll
    for (int ks = 0; ks < 8; ++ks) aq[ks] = *(const short8*)(qp + ks * 16);
  }

  // per-lane LDS read bases (all reads are base + compile-time immediate)
  const unsigned short* ksl = Ks + lane * 8;
  const unsigned short* vsl = Vs + lane * 8;
  const unsigned short* g2p =
      G2 + ((size_t)(tbase >> 5) * S_LEN + q0 + wv * 32 + l31) * 32 + hi * 16;

  float l_acc = 0.0f;
  f32x16 z16;
#pragma unroll
  for (int j = 0; j < 16; ++j) z16[j] = 0.0f;   // loop-invariant zero C operand
  f32x16 o[4];
#pragma unroll
  for (int d = 0; d < 4; ++d) o[d] = z16;

  // prologue: stage tile 0, then advance
#pragma unroll
  for (int c = 0; c < 4; ++c) {
    gld_lds16(gK + c * 512, lKb + c * 512);
    gld_lds16(gV + c * 512, lVb + c * 512);
  }
  gK += 16 * 512;
  gV += 16 * 512;
  __syncthreads();

  for (int it = 0; it < niter; ++it) {
    // G loads (idx = hi*16 + reg matches the 32x32 C register order)
    short8 gg[4];
    gg[0] = *(const short8*)(g2p);
    gg[1] = *(const short8*)(g2p + 8);
    gg[2] = *(const short8*)(g2p + (size_t)S_LEN * 32);
    gg[3] = *(const short8*)(g2p + (size_t)S_LEN * 32 + 8);
    g2p += (size_t)2 * S_LEN * 32;

    // S^T = K Q^T (exp2 domain): col = q = l31, row = t. ks=0 peeled onto zero C.
    f32x16 sv[2];
    __builtin_amdgcn_s_setprio(1);
    {
      short8 k0 = *(const short8*)(ksl + 0 * 512);
      short8 k1 = *(const short8*)(ksl + 1 * 512);
      sv[0] = __builtin_amdgcn_mfma_f32_32x32x16_bf16(k0, aq[0], z16, 0, 0, 0);
      sv[1] = __builtin_amdgcn_mfma_f32_32x32x16_bf16(k1, aq[0], z16, 0, 0, 0);
    }
#pragma unroll
    for (int ks = 1; ks < 8; ++ks) {
      short8 k0 = *(const short8*)(ksl + (2 * ks) * 512);
      short8 k1 = *(const short8*)(ksl + (2 * ks + 1) * 512);
      sv[0] = __builtin_amdgcn_mfma_f32_32x32x16_bf16(k0, aq[ks], sv[0], 0, 0, 0);
      sv[1] = __builtin_amdgcn_mfma_f32_32x32x16_bf16(k1, aq[ks], sv[1], 0, 0, 0);
    }
    __builtin_amdgcn_s_setprio(0);
    __syncthreads();   // A: Ks consumed; drains V(t) staging + G loads

    if (it + 1 < niter) {
#pragma unroll
      for (int c = 0; c < 4; ++c)
        gld_lds16(gK + c * 512, lKb + c * 512);
      gK += 16 * 512;
    }

    // softmax (fixed-base exp2, masked -> 0) + in-register P relayout (T12)
    short8 pa[4];
#pragma unroll
    for (int b = 0; b < 2; ++b) {
      float p[16];
#pragma unroll
      for (int r = 0; r < 16; ++r) {
        float gv = bf16_to_f32((unsigned short)gg[2 * b + (r >> 3)][r & 7]);
        float x = (gv < 0.0f) ? -1e9f : sv[b][r];
        float e = EXP2F(x);
        l_acc += e;
        p[r] = e * gv;
      }
#pragma unroll
      for (int c2 = 0; c2 < 2; ++c2) {
        unsigned X0 = cvtpk_bf16(p[8 * c2 + 0], p[8 * c2 + 1]);
        unsigned X1 = cvtpk_bf16(p[8 * c2 + 2], p[8 * c2 + 3]);
        unsigned X2 = cvtpk_bf16(p[8 * c2 + 4], p[8 * c2 + 5]);
        unsigned X3 = cvtpk_bf16(p[8 * c2 + 6], p[8 * c2 + 7]);
        pl32swap(X0, X2);   // -> X0 = frag word0 (j=0,1), X2 = word2 (j=4,5)
        pl32swap(X1, X3);   // -> X1 = word1 (j=2,3),      X3 = word3 (j=6,7)
        union { unsigned w[4]; short8 s8; } u;
        u.w[0] = X0; u.w[1] = X1; u.w[2] = X2; u.w[3] = X3;
        pa[2 * b + c2] = u.s8;
      }
    }

    // O += P V  (A = pa from registers, B = V' fragments from LDS, linear reads)
    __builtin_amdgcn_s_setprio(1);
#pragma unroll
    for (int db = 0; db < 4; ++db) {
#pragma unroll
      for (int tc = 0; tc < 4; ++tc) {
        short8 bv8 = *(const short8*)(vsl + (db * 4 + tc) * 512);
        o[db] = __builtin_amdgcn_mfma_f32_32x32x16_bf16(pa[tc], bv8, o[db], 0, 0, 0);
      }
    }
    __builtin_amdgcn_s_setprio(0);
    __syncthreads();   // B: Vs consumed; drains K(t+1) staging

    if (it + 1 < niter) {
#pragma unroll
      for (int c = 0; c < 4; ++c)
        gld_lds16(gV + c * 512, lVb + c * 512);
      gV += 16 * 512;
    }
  }

  // epilogue: l reduce over hi-halves; write partials
  l_acc += __shfl_xor(l_acc, 32, 64);
  if (hi == 0)
    LP[((size_t)ts * NH + h) * S_LEN + q0 + wv * 32 + l31] = l_acc;
  unsigned short* op = OP + (size_t)ts * S_LEN * E_DIM;
#pragma unroll
  for (int db = 0; db < 4; ++db)
#pragma unroll
    for (int r = 0; r < 16; ++r) {
      int gr = q0 + wv * 32 + (r & 3) + 8 * (r >> 2) + 4 * hi;
      int gc = h * DKD + db * 32 + l31;
      op[(size_t)gr * E_DIM + gc] = f32_to_bf16(o[db][r]);
    }
}

// ---------------- combine t-split partials: Z = (O0+O1+O2)/(l0+l1+l2) ----------------
__global__ __launch_bounds__(256) void combine(const unsigned short* __restrict__ OP,
                                               const float* __restrict__ LP,
                                               unsigned short* __restrict__ Z) {
  const int s = blockIdx.x;
  const int e0 = threadIdx.x * 4;
  const int h = e0 >> 7;
  const float l = LP[(size_t)h * S_LEN + s] +
                  LP[(size_t)(NH + h) * S_LEN + s] +
                  LP[(size_t)(2 * NH + h) * S_LEN + s];
  const float inv = 1.0f / l;
  const size_t sz = (size_t)S_LEN * E_DIM;
  ushort4v a = *(const ushort4v*)(OP + (size_t)s * E_DIM + e0);
  ushort4v b = *(const ushort4v*)(OP + sz + (size_t)s * E_DIM + e0);
  ushort4v c = *(const ushort4v*)(OP + 2 * sz + (size_t)s * E_DIM + e0);
  ushort4v pk;
#pragma unroll
  for (int j = 0; j < 4; ++j)
    pk[j] = f32_to_bf16((bf16_to_f32(a[j]) + bf16_to_f32(b[j]) + bf16_to_f32(c[j])) * inv);
  *(ushort4v*)(Z + (size_t)s * E_DIM + e0) = pk;
}

// ---------------- LayerNorm ----------------
__global__ __launch_bounds__(256) void ln_fwd(const float* __restrict__ Y,
                                              const float* __restrict__ g,
                                              const float* __restrict__ b,
                                              float* __restrict__ out) {
  const int row = blockIdx.x;
  const int tid = threadIdx.x;
  const float* y = Y + (size_t)row * E_DIM;
  f32x4 v = *(const f32x4*)(y + tid * 4);
  float s = v.x + v.y + v.z + v.w;
  float s2 = v.x * v.x + v.y * v.y + v.z * v.z + v.w * v.w;
#pragma unroll
  for (int off = 32; off > 0; off >>= 1) {
    s += __shfl_down(s, off, 64);
    s2 += __shfl_down(s2, off, 64);
  }
  __shared__ float red[8];
  __shared__ float mu_s, rs_s;
  const int wave = tid >> 6, lane = tid & 63;
  if (lane == 0) { red[wave] = s; red[4 + wave] = s2; }
  __syncthreads();
  if (tid == 0) {
    float ts = red[0] + red[1] + red[2] + red[3];
    float ts2 = red[4] + red[5] + red[6] + red[7];
    float mu = ts * (1.0f / E_DIM);
    float var = ts2 * (1.0f / E_DIM) - mu * mu;
    mu_s = mu;
    rs_s = rsqrtf(var + 1e-5f);
  }
  __syncthreads();
  const float mu = mu_s, rs = rs_s;
  f32x4 gg = *(const f32x4*)(g + tid * 4);
  f32x4 bb = *(const f32x4*)(b + tid * 4);
  f32x4 ov;
  ov.x = (v.x - mu) * rs * gg.x + bb.x;
  ov.y = (v.y - mu) * rs * gg.y + bb.y;
  ov.z = (v.z - mu) * rs * gg.z + bb.z;
  ov.w = (v.w - mu) * rs * gg.w + bb.w;
  *(f32x4*)(out + (size_t)row * E_DIM + tid * 4) = ov;
}

extern "C" void kernel_launch(void* const* d_in, const int* in_sizes, int n_in,
                              void* d_out, int out_size, void* d_ws, size_t ws_size,
                              hipStream_t stream) {
  const float* q   = (const float*)d_in[0];
  const float* k   = (const float*)d_in[1];
  const float* v   = (const float*)d_in[2];
  const int*  mask = (const int*)d_in[3];
  const float* gp  = (const float*)d_in[4];
  const float* Wq  = (const float*)d_in[5];
  const float* bq  = (const float*)d_in[6];
  const float* Wk  = (const float*)d_in[7];
  const float* bk  = (const float*)d_in[8];
  const float* Wv  = (const float*)d_in[9];
  const float* bv  = (const float*)d_in[10];
  const float* Wo  = (const float*)d_in[11];
  const float* bo  = (const float*)d_in[12];
  const float* lng = (const float*)d_in[13];
  const float* lnb = (const float*)d_in[14];

  char* ws = (char*)d_ws;
  const size_t MB = 1024 * 1024;
  // layout, 88 MB peak (lifetimes disjoint where overlapped):
  unsigned short* WOB  = (unsigned short*)(ws + 0);      // Wo bf16 [0,2)
  unsigned short* WQKV = (unsigned short*)(ws + 2 * MB); // Wq,Wk,Wv [2,8) dead after proj
  float* LPb = (float*)(ws + 2 * MB);                    // [2,2.4) l-partials (after proj)
  unsigned short* XB = (unsigned short*)(ws + 8 * MB);   // q,k,v bf16 [8,32) dead after proj
  unsigned short* GT = (unsigned short*)(ws + 8 * MB);   // [8,40) G2 built after proj
  unsigned short* QH = (unsigned short*)(ws + 40 * MB);  // [40,48) dead after attn
  unsigned short* KH = (unsigned short*)(ws + 48 * MB);  // [48,56) K' frag-major
  unsigned short* VT = (unsigned short*)(ws + 56 * MB);  // [56,64) V' frag-major
  unsigned short* ZB = (unsigned short*)(ws + 40 * MB);  // [40,48) written by combine
  float* YF = (float*)(ws + 48 * MB);                    // [48,64) written by out_proj
  unsigned short* OP = (unsigned short*)(ws + 64 * MB);  // [64,88) O-partials (3x8MB)

  cvt_all<<<dim3(4096, 7), 256, 0, stream>>>(q, k, v, Wq, Wk, Wv, Wo,
                                             (unsigned short*)ws);
  proj_qkv<<<dim3(32, 8, 3), 256, 0, stream>>>(XB, WQKV, bq, bk, bv, QH, KH, VT);
  build_gt<<<dim3(64, 64), 256, 0, stream>>>(mask, gp, GT);   // overwrites XB
  attn_fwd<<<dim3(32, 8, 3), 256, 0, stream>>>(QH, KH, VT, GT, OP, LPb);
  combine<<<S_LEN, 256, 0, stream>>>(OP, LPb, ZB);
  out_proj<<<dim3(32, 16), 256, 0, stream>>>(ZB, WOB, bo, q, YF);
  ln_fwd<<<S_LEN, 256, 0, stream>>>(YF, lng, lnb, (float*)d_out);
}